// Round 9
// baseline (457.125 us; speedup 1.0000x reference)
//
#include <hip/hip_runtime.h>
#include <cstdint>
#include <cstddef>

#define IN_CH 128
#define HID 64
#define HEADS 8
#define OUT_CH 40
#define NEG 0.2f
#define PAD 128   // max degree bucket; deg = Poisson(32)+1, P(deg>127) ~ 1e-35
#define NBLK 512  // grid: 2 blocks/CU x 256 CUs, co-residency guaranteed by __launch_bounds__(256,2)
#define NTHR 256

typedef __attribute__((ext_vector_type(8))) short bf16x8;
typedef __attribute__((ext_vector_type(4))) float f32x4;

#define MFMA(a, b, c) __builtin_amdgcn_mfma_f32_16x16x32_bf16(a, b, c, 0, 0, 0)

__device__ inline unsigned short f2bf(float f) {
    unsigned u = __float_as_uint(f);
    unsigned r = (u + 0x7FFFu + ((u >> 16) & 1u)) >> 16;
    return (unsigned short)r;
}
__device__ inline float bf2f(unsigned short b) {
    return __uint_as_float((unsigned)b << 16);
}
__device__ inline bf16x8 ldb8(const unsigned short* p) {
    return *reinterpret_cast<const bf16x8*>(p);
}

// -------- grid barrier (ROCm cooperative-sync pattern, one-shot counters) --------
__device__ __forceinline__ void gridbar(int* bar) {
    __syncthreads();
    if (threadIdx.x == 0) {
        __threadfence();  // release: flush this XCD's L2 so other XCDs see our writes
        if (atomicAdd(bar, 1) != (int)gridDim.x - 1) {
            long iters = 0;
            while (__hip_atomic_load(bar, __ATOMIC_ACQUIRE, __HIP_MEMORY_SCOPE_AGENT) < (int)gridDim.x) {
                __builtin_amdgcn_s_sleep(2);
                if (++iters > 200000000L) break;  // failsafe: fail loud instead of hanging
            }
        }
        __threadfence();  // acquire: invalidate caches before reading others' data
    }
    __syncthreads();
}

// -------- shared memory union across phases (max 28.9KB) --------
struct SMemC { unsigned short h0s[16][72]; };
struct SMemD { int srcb[PAD]; float sb[PAD][8]; float mx[8]; float den[8]; float adl[8]; float accsh[512]; };
struct SMemE { unsigned short h1s[16][520]; float part[3][4][64][4]; };
struct SMemF { float w2s[HID * OUT_CH]; float cosh_[4][HID]; };
union __align__(16) SMem {
    SMemC c;
    SMemD d[2];
    SMemE e;
    SMemF f;
};

__global__ void k_prezero(int* __restrict__ bars) {
    if (threadIdx.x < 8) bars[threadIdx.x] = 0;
}

__global__ __launch_bounds__(NTHR, 2) void k_mega(
    const float* __restrict__ x, const int* __restrict__ ei,
    const float* __restrict__ W1, const float* __restrict__ b1,
    const float* __restrict__ Wc1, const float* __restrict__ as1, const float* __restrict__ ad1,
    const float* __restrict__ bc1,
    const float* __restrict__ Wc2, const float* __restrict__ as2, const float* __restrict__ ad2,
    const float* __restrict__ bc2,
    const float* __restrict__ W2, const float* __restrict__ b2,
    float* __restrict__ out,
    int* __restrict__ cursor, int* __restrict__ csrc,
    unsigned short* __restrict__ W1T, unsigned short* __restrict__ Wc1T,
    unsigned short* __restrict__ Wc2T, unsigned short* __restrict__ vaT,
    unsigned short* __restrict__ h0b, float* __restrict__ asrc1, float* __restrict__ adst1,
    unsigned short* __restrict__ aggb, unsigned short* __restrict__ hc2b,
    float* __restrict__ asrc2, float* __restrict__ adst2,
    int* __restrict__ bars, int N, int E, int T) {

    __shared__ SMem sm;
    int bid = blockIdx.x, tid = threadIdx.x;
    int gid = bid * NTHR + tid;
    int w = tid >> 6, l = tid & 63;
    int c = l & 15, g = l >> 4;

    // ================= phase A: zero cursor + weight transposes + vaT =================
    {
        int i = gid;
        if (i < N) {
            cursor[i] = 0;
        } else {
            i -= N;
            if (i < 64 * 128) {
                int j = i >> 7, k = i & 127;
                W1T[i] = f2bf(W1[k * 64 + j]);
            } else {
                i -= 64 * 128;
                if (i < 512 * 64) {
                    int j = i >> 6, k = i & 63;
                    Wc1T[i] = f2bf(Wc1[(size_t)k * 512 + j]);
                } else {
                    i -= 512 * 64;
                    if (i < 64 * 512) {
                        int j = i >> 9, k = i & 511;
                        Wc2T[i] = f2bf(Wc2[(size_t)k * 64 + j]);
                    } else {
                        i -= 64 * 512;
                        if (i < 1024) {
                            int t = i >> 6, k2 = i & 63;
                            int h = t & 7;
                            const float* a = (t < 8) ? as1 : ad1;
                            float sum = 0.f;
                            for (int c2 = 0; c2 < 64; ++c2)
                                sum += Wc1[(size_t)k2 * 512 + h * 64 + c2] * a[h * 64 + c2];
                            vaT[t * 64 + k2] = f2bf(sum);
                        }
                    }
                }
            }
        }
    }
    gridbar(&bars[0]);

    // ================= phase B+C: CSR fill (atomics) + lin1 GEMM + alpha1 =================
    for (int e = gid; e < T; e += NBLK * NTHR) {
        int s, d;
        if (e < E) { s = ei[e]; d = ei[E + e]; } else { s = d = e - E; }
        int pos = atomicAdd(&cursor[d], 1);
        csrc[(size_t)d * PAD + pos] = s;
    }
    for (int t = bid; t < (N + 15) / 16; t += NBLK) {
        int m0 = t * 16;
        __syncthreads();   // protect h0s reuse across iterations
        int xr = m0 + c; if (xr >= N) xr = N - 1;
        bf16x8 af[4];
        const float* arow = x + (size_t)xr * 128 + 8 * g;
#pragma unroll
        for (int ks = 0; ks < 4; ++ks) {
            float4 f0 = *(const float4*)(arow + 32 * ks);
            float4 f1 = *(const float4*)(arow + 32 * ks + 4);
            bf16x8 tt;
            tt[0] = (short)f2bf(f0.x); tt[1] = (short)f2bf(f0.y);
            tt[2] = (short)f2bf(f0.z); tt[3] = (short)f2bf(f0.w);
            tt[4] = (short)f2bf(f1.x); tt[5] = (short)f2bf(f1.y);
            tt[6] = (short)f2bf(f1.z); tt[7] = (short)f2bf(f1.w);
            af[ks] = tt;
        }
        f32x4 acc = {};
        const unsigned short* brow = W1T + (size_t)(16 * w + c) * 128 + 8 * g;
#pragma unroll
        for (int ks = 0; ks < 4; ++ks) acc = MFMA(af[ks], ldb8(brow + 32 * ks), acc);
        int j = 16 * w + c;
        float bj = b1[j];
#pragma unroll
        for (int r = 0; r < 4; ++r) {
            float v = fmaxf(acc[r] + bj, 0.f);
            unsigned short us = f2bf(v);
            int row = m0 + 4 * g + r;
            if (row < N) h0b[(size_t)row * 64 + j] = us;
            sm.c.h0s[4 * g + r][j] = us;
        }
        __syncthreads();
        if (w == 0) {
            bf16x8 a0 = ldb8(&sm.c.h0s[c][8 * g]);
            bf16x8 a1 = ldb8(&sm.c.h0s[c][32 + 8 * g]);
            bf16x8 b0 = ldb8(&vaT[c * 64 + 8 * g]);
            bf16x8 b1v = ldb8(&vaT[c * 64 + 32 + 8 * g]);
            f32x4 al = {};
            al = MFMA(a0, b0, al);
            al = MFMA(a1, b1v, al);
#pragma unroll
            for (int r = 0; r < 4; ++r) {
                int n = m0 + 4 * g + r;
                if (n < N) {
                    if (c < 8) asrc1[n * 8 + c] = al[r];
                    else       adst1[n * 8 + (c - 8)] = al[r];
                }
            }
        }
    }
    gridbar(&bars[1]);

    // ================= phase D: conv1 per-head softmax aggregation =================
    {
        SMemD& D = sm.d[tid >> 7];
        int st = tid & 127;
        int lane = st & 63, wv = st >> 6;
        int half = lane >> 5, cl = lane & 31;
        int npair = (N + 1) / 2;
        for (int p = bid; p < npair; p += NBLK) {
            int n = 2 * p + (tid >> 7);
            int deg = (n < N) ? cursor[n] : 0;
            __syncthreads();   // protect reuse from previous iteration
            if (st < 8 && n < N) D.adl[st] = adst1[n * 8 + st];
            __syncthreads();
            if (st < deg) {
                int s = csrc[(size_t)n * PAD + st];
                D.srcb[st] = s;
                const float4* ap = (const float4*)&asrc1[(size_t)s * 8];
                float4 a0 = ap[0], a1 = ap[1];
                float v;
                v = a0.x + D.adl[0]; D.sb[st][0] = (v >= 0.f) ? v : NEG * v;
                v = a0.y + D.adl[1]; D.sb[st][1] = (v >= 0.f) ? v : NEG * v;
                v = a0.z + D.adl[2]; D.sb[st][2] = (v >= 0.f) ? v : NEG * v;
                v = a0.w + D.adl[3]; D.sb[st][3] = (v >= 0.f) ? v : NEG * v;
                v = a1.x + D.adl[4]; D.sb[st][4] = (v >= 0.f) ? v : NEG * v;
                v = a1.y + D.adl[5]; D.sb[st][5] = (v >= 0.f) ? v : NEG * v;
                v = a1.z + D.adl[6]; D.sb[st][6] = (v >= 0.f) ? v : NEG * v;
                v = a1.w + D.adl[7]; D.sb[st][7] = (v >= 0.f) ? v : NEG * v;
            }
            __syncthreads();
            if (st < 64) {
                int hh = st & 7, idx = st >> 3;
                float m = -1e30f;
                for (int i = idx; i < deg; i += 8) m = fmaxf(m, D.sb[i][hh]);
                m = fmaxf(m, __shfl_xor(m, 8));
                m = fmaxf(m, __shfl_xor(m, 16));
                m = fmaxf(m, __shfl_xor(m, 32));
                if (st < 8) D.mx[st] = m;
            }
            __syncthreads();
            if (st < 64) {
                int hh = st & 7, idx = st >> 3;
                float mh = D.mx[hh];
                float dsum = 0.f;
                for (int i = idx; i < deg; i += 8) {
                    float ev = __expf(D.sb[i][hh] - mh);
                    D.sb[i][hh] = ev;
                    dsum += ev;
                }
                dsum += __shfl_xor(dsum, 8);
                dsum += __shfl_xor(dsum, 16);
                dsum += __shfl_xor(dsum, 32);
                if (st < 8) D.den[st] = dsum + 1e-16f;
            }
            __syncthreads();
            float accA[8] = {0.f, 0.f, 0.f, 0.f, 0.f, 0.f, 0.f, 0.f};
            float accB[8] = {0.f, 0.f, 0.f, 0.f, 0.f, 0.f, 0.f, 0.f};
            for (int i = 2 * wv; i < deg; i += 4) {
                int e = i + half;
                float vx = 0.f, vy = 0.f;
                float4 w0 = {0.f, 0.f, 0.f, 0.f}, w1 = {0.f, 0.f, 0.f, 0.f};
                if (e < deg) {
                    unsigned u = *(const unsigned*)&h0b[(size_t)D.srcb[e] * 64 + 2 * cl];
                    vx = bf2f((unsigned short)(u & 0xFFFFu));
                    vy = bf2f((unsigned short)(u >> 16));
                    w0 = *(const float4*)&D.sb[e][0];
                    w1 = *(const float4*)&D.sb[e][4];
                }
                accA[0] += w0.x * vx; accB[0] += w0.x * vy;
                accA[1] += w0.y * vx; accB[1] += w0.y * vy;
                accA[2] += w0.z * vx; accB[2] += w0.z * vy;
                accA[3] += w0.w * vx; accB[3] += w0.w * vy;
                accA[4] += w1.x * vx; accB[4] += w1.x * vy;
                accA[5] += w1.y * vx; accB[5] += w1.y * vy;
                accA[6] += w1.z * vx; accB[6] += w1.z * vy;
                accA[7] += w1.w * vx; accB[7] += w1.w * vy;
            }
#pragma unroll
            for (int h = 0; h < 8; ++h) {
                accA[h] += __shfl_xor(accA[h], 32);
                accB[h] += __shfl_xor(accB[h], 32);
            }
            __syncthreads();
            if (wv == 1 && half == 0) {
#pragma unroll
                for (int h = 0; h < 8; ++h) {
                    D.accsh[h * 64 + 2 * cl] = accA[h];
                    D.accsh[h * 64 + 2 * cl + 1] = accB[h];
                }
            }
            __syncthreads();
            if (wv == 0 && half == 0 && n < N) {
#pragma unroll
                for (int h = 0; h < 8; ++h) {
                    float t0 = (accA[h] + D.accsh[h * 64 + 2 * cl]) / D.den[h];
                    float t1 = (accB[h] + D.accsh[h * 64 + 2 * cl + 1]) / D.den[h];
                    unsigned uo = (unsigned)f2bf(t0) | ((unsigned)f2bf(t1) << 16);
                    *(unsigned*)&aggb[(size_t)n * 512 + h * 64 + 2 * cl] = uo;
                }
            }
        }
    }
    gridbar(&bars[2]);

    // ================= phase E: post1 (per-head GEMM, h1 in LDS) + linc2 + alpha2 =================
    for (int t = bid; t < (N + 15) / 16; t += NBLK) {
        int m0 = t * 16;
        __syncthreads();   // protect h1s reuse across iterations
#pragma unroll
        for (int hl = 0; hl < 2; ++hl) {
            int h = 2 * w + hl;
            const unsigned short* arow = aggb + (size_t)(m0 + c) * 512 + h * 64 + 8 * g;
            bf16x8 af0 = ldb8(arow), af1 = ldb8(arow + 32);
            f32x4 acc[4] = {};
#pragma unroll
            for (int nt = 0; nt < 4; ++nt) {
                const unsigned short* brow = Wc1T + (size_t)(h * 64 + 16 * nt + c) * 64 + 8 * g;
                acc[nt] = MFMA(af0, ldb8(brow), acc[nt]);
                acc[nt] = MFMA(af1, ldb8(brow + 32), acc[nt]);
            }
#pragma unroll
            for (int nt = 0; nt < 4; ++nt) {
                int j = h * 64 + 16 * nt + c;
                float bj = bc1[j];
#pragma unroll
                for (int r = 0; r < 4; ++r) {
                    float v = acc[nt][r] + bj;
                    v = (v > 0.f) ? v : __expf(v) - 1.f;
                    sm.e.h1s[4 * g + r][j] = f2bf(v);
                }
            }
        }
        __syncthreads();
        f32x4 acc2[4] = {};
#pragma unroll
        for (int ks = 0; ks < 4; ++ks) {
            bf16x8 af = ldb8(&sm.e.h1s[c][128 * w + 32 * ks + 8 * g]);
#pragma unroll
            for (int nt = 0; nt < 4; ++nt) {
                const unsigned short* brow = Wc2T + (size_t)(16 * nt + c) * 512 + 128 * w + 32 * ks + 8 * g;
                acc2[nt] = MFMA(af, ldb8(brow), acc2[nt]);
            }
        }
        if (w > 0) {
#pragma unroll
            for (int nt = 0; nt < 4; ++nt)
                *(f32x4*)&sm.e.part[w - 1][nt][l][0] = acc2[nt];
        }
        __syncthreads();
        if (w == 0) {
#pragma unroll
            for (int nt = 0; nt < 4; ++nt)
#pragma unroll
                for (int i = 0; i < 3; ++i) {
                    f32x4 pp = *(const f32x4*)&sm.e.part[i][nt][l][0];
                    acc2[nt][0] += pp[0]; acc2[nt][1] += pp[1];
                    acc2[nt][2] += pp[2]; acc2[nt][3] += pp[3];
                }
            float ps[4] = {0.f, 0.f, 0.f, 0.f}, pd[4] = {0.f, 0.f, 0.f, 0.f};
#pragma unroll
            for (int nt = 0; nt < 4; ++nt) {
                int j = 16 * nt + c;
                float aj = as2[j], dj = ad2[j];
#pragma unroll
                for (int r = 0; r < 4; ++r) {
                    float v = acc2[nt][r];
                    hc2b[(size_t)(m0 + 4 * g + r) * 64 + j] = f2bf(v);
                    ps[r] += v * aj;
                    pd[r] += v * dj;
                }
            }
#pragma unroll
            for (int r = 0; r < 4; ++r) {
                float s = ps[r], d = pd[r];
                s += __shfl_xor(s, 1); s += __shfl_xor(s, 2); s += __shfl_xor(s, 4); s += __shfl_xor(s, 8);
                d += __shfl_xor(d, 1); d += __shfl_xor(d, 2); d += __shfl_xor(d, 4); d += __shfl_xor(d, 8);
                if (c == 0) {
                    int n = m0 + 4 * g + r;
                    asrc2[n] = s;
                    adst2[n] = d;
                }
            }
        }
    }
    gridbar(&bars[3]);

    // ================= phase F: conv2 softmax-agg + final GEMM =================
    {
        for (int i = tid; i < HID * OUT_CH; i += NTHR) sm.f.w2s[i] = W2[i];
        int lane = tid & 63, nl = tid >> 6;
        int half = lane >> 5, cl = lane & 31;
        int nquad = (N + 3) / 4;
        for (int q = bid; q < nquad; q += NBLK) {
            __syncthreads();   // w2s ready / cosh_ reuse protection
            int n = q * 4 + nl;
            if (n < N) {
                int deg = cursor[n];
                float ad = adst2[n];
                float rm = -1e30f, rden = 0.f;
                float ax = 0.f, ay = 0.f;
                for (int base = 0; base < deg; base += 64) {
                    int cnt = min(64, deg - base);
                    int s = 0;
                    float sc = -1e30f;
                    if (lane < cnt) {
                        s = csrc[(size_t)n * PAD + base + lane];
                        float v = asrc2[s] + ad;
                        sc = (v >= 0.f) ? v : NEG * v;
                    }
                    float m = sc;
#pragma unroll
                    for (int mm = 1; mm < 64; mm <<= 1) m = fmaxf(m, __shfl_xor(m, mm));
                    float nmv = fmaxf(rm, m);
                    float scale = __expf(rm - nmv);
                    float p = (lane < cnt) ? __expf(sc - nmv) : 0.f;
                    float d = p;
#pragma unroll
                    for (int mm = 1; mm < 64; mm <<= 1) d += __shfl_xor(d, mm);
                    rden = rden * scale + d;
                    rm = nmv;
                    ax *= scale; ay *= scale;
                    for (int i = 0; i < cnt; i += 2) {
                        int idx = i + half;
                        float pi = __shfl(p, idx);
                        int si = __shfl(s, idx);
                        unsigned u = *(const unsigned*)&hc2b[(size_t)si * 64 + 2 * cl];
                        ax += pi * bf2f((unsigned short)(u & 0xFFFFu));
                        ay += pi * bf2f((unsigned short)(u >> 16));
                    }
                }
                ax += __shfl_xor(ax, 32);
                ay += __shfl_xor(ay, 32);
                if (half == 0) {
                    float inv = 1.f / (rden + 1e-16f);
                    sm.f.cosh_[nl][2 * cl] = ax * inv + bc2[2 * cl];
                    sm.f.cosh_[nl][2 * cl + 1] = ay * inv + bc2[2 * cl + 1];
                }
            }
            __syncthreads();
            if (tid < 160) {
                int nn = tid / 40, j = tid % 40;
                int no = q * 4 + nn;
                if (no < N) {
                    float s = b2[j];
#pragma unroll 8
                    for (int k = 0; k < HID; ++k) s += sm.f.cosh_[nn][k] * sm.f.w2s[k * OUT_CH + j];
                    out[(size_t)no * OUT_CH + j] = s;
                }
            }
        }
    }
}

// ---------------- host ----------------

extern "C" void kernel_launch(void* const* d_in, const int* in_sizes, int n_in,
                              void* d_out, int out_size, void* d_ws, size_t ws_size,
                              hipStream_t stream) {
    const float* x   = (const float*)d_in[0];
    const int*   ei  = (const int*)d_in[1];
    const float* W1  = (const float*)d_in[2];
    const float* b1  = (const float*)d_in[3];
    const float* Wc1 = (const float*)d_in[4];
    const float* as1 = (const float*)d_in[5];
    const float* ad1 = (const float*)d_in[6];
    const float* bc1 = (const float*)d_in[7];
    const float* Wc2 = (const float*)d_in[8];
    const float* as2 = (const float*)d_in[9];
    const float* ad2 = (const float*)d_in[10];
    const float* bc2 = (const float*)d_in[11];
    const float* W2  = (const float*)d_in[12];
    const float* b2  = (const float*)d_in[13];

    const int N = in_sizes[0] / IN_CH;
    const int E = in_sizes[1] / 2;
    const int T = E + N;

    char* base = (char*)d_ws;
    size_t off = 0;
    auto carve = [&](size_t bytes) -> void* {
        off = (off + 255) & ~(size_t)255;
        void* r = base + off;
        off += bytes;
        return r;
    };
    int* bars       = (int*)carve(8 * 4);
    int* cursor     = (int*)carve((size_t)N * 4);
    int* csrc       = (int*)carve((size_t)N * PAD * 4);
    unsigned short* W1T  = (unsigned short*)carve((size_t)64 * 128 * 2);
    unsigned short* Wc1T = (unsigned short*)carve((size_t)512 * 64 * 2);
    unsigned short* Wc2T = (unsigned short*)carve((size_t)64 * 512 * 2);
    unsigned short* vaT  = (unsigned short*)carve((size_t)16 * 64 * 2);
    unsigned short* h0b  = (unsigned short*)carve((size_t)N * 64 * 2);
    float* asrc1    = (float*)carve((size_t)N * 8 * 4);
    float* adst1    = (float*)carve((size_t)N * 8 * 4);
    unsigned short* aggb = (unsigned short*)carve((size_t)N * 512 * 2);
    unsigned short* hc2b = (unsigned short*)carve((size_t)N * 64 * 2);
    float* asrc2    = (float*)carve((size_t)N * 4);
    float* adst2    = (float*)carve((size_t)N * 4);

    k_prezero<<<1, 64, 0, stream>>>(bars);
    k_mega<<<NBLK, NTHR, 0, stream>>>(x, ei, W1, b1, Wc1, as1, ad1, bc1,
                                      Wc2, as2, ad2, bc2, W2, b2, (float*)d_out,
                                      cursor, csrc, W1T, Wc1T, Wc2T, vaT,
                                      h0b, asrc1, adst1, aggb, hc2b, asrc2, adst2,
                                      bars, N, E, T);
}

// Round 10
// 95.374 us; speedup vs baseline: 4.7930x; 4.7930x over previous
//
#include <hip/hip_runtime.h>
#include <cstdint>
#include <cstddef>

#define IN_CH 128
#define HID 64
#define HEADS 8
#define OUT_CH 40
#define NEG 0.2f
#define PAD 128   // max degree bucket; deg = Poisson(32)+1, P(deg>127) ~ 1e-35

typedef __attribute__((ext_vector_type(8))) short bf16x8;
typedef __attribute__((ext_vector_type(4))) float f32x4;

#define MFMA(a, b, c) __builtin_amdgcn_mfma_f32_16x16x32_bf16(a, b, c, 0, 0, 0)

__device__ inline unsigned short f2bf(float f) {
    unsigned u = __float_as_uint(f);
    unsigned r = (u + 0x7FFFu + ((u >> 16) & 1u)) >> 16;
    return (unsigned short)r;
}
__device__ inline float bf2f(unsigned short b) {
    return __uint_as_float((unsigned)b << 16);
}
__device__ inline bf16x8 ldb8(const unsigned short* p) {
    return *reinterpret_cast<const bf16x8*>(p);
}

// ---------------- init: zero cursor + weight transposes (bf16) + vaT = [16][64] alpha weights ----------------

__global__ void k_init(const float* __restrict__ W1,
                       const float* __restrict__ Wc1, const float* __restrict__ Wc2,
                       const float* __restrict__ as1, const float* __restrict__ ad1,
                       int* __restrict__ cursor,
                       unsigned short* __restrict__ W1T,
                       unsigned short* __restrict__ Wc1T, unsigned short* __restrict__ Wc2T,
                       unsigned short* __restrict__ vaT, int N) {
    int i = blockIdx.x * 256 + threadIdx.x;
    if (i < N) { cursor[i] = 0; return; }
    i -= N;
    if (i < 64 * 128) {  // W1T[j][k] = W1[k][j]
        int j = i >> 7, k = i & 127;
        W1T[i] = f2bf(W1[k * 64 + j]);
        return;
    }
    i -= 64 * 128;
    if (i < 512 * 64) {  // Wc1T[j][k] = Wc1[k][j]
        int j = i >> 6, k = i & 63;
        Wc1T[i] = f2bf(Wc1[(size_t)k * 512 + j]);
        return;
    }
    i -= 512 * 64;
    if (i < 64 * 512) {  // Wc2T[j][k] = Wc2[k][j]
        int j = i >> 9, k = i & 511;
        Wc2T[i] = f2bf(Wc2[(size_t)k * 64 + j]);
        return;
    }
    i -= 64 * 512;
    if (i < 1024) {  // vaT[t][k]: t<8 -> src head t, t>=8 -> dst head t-8
        int t = i >> 6, k = i & 63;
        int h = t & 7;
        const float* a = (t < 8) ? as1 : ad1;
        float sum = 0.f;
        for (int c = 0; c < 64; ++c) sum += Wc1[(size_t)k * 512 + h * 64 + c] * a[h * 64 + c];
        vaT[t * 64 + k] = f2bf(sum);
    }
}

// ---------------- lin1 (MFMA) + MFMA alpha1 + merged CSR fill ----------------
// blocks [0, NB): GEMM tile of 16 rows; blocks [NB, NB+FB): padded CSR fill

__global__ __launch_bounds__(256) void k_lin1m(const float* __restrict__ x,
                                               const unsigned short* __restrict__ W1T,
                                               const float* __restrict__ b1,
                                               const unsigned short* __restrict__ vaT,
                                               unsigned short* __restrict__ h0b,
                                               float* __restrict__ asrc, float* __restrict__ adst,
                                               const int* __restrict__ ei, int E, int T,
                                               int* __restrict__ cursor, int* __restrict__ csrc,
                                               int N, int NB) {
    __shared__ unsigned short h0s[16][72];   // 2.25KB, stride 72 keeps 16B row alignment
    if (blockIdx.x >= NB) {
        // ---- CSR fill role ----
        int e = (blockIdx.x - NB) * 256 + threadIdx.x;
        if (e < T) {
            int s, d;
            if (e < E) { s = ei[e]; d = ei[E + e]; } else { s = d = e - E; }
            int pos = atomicAdd(&cursor[d], 1);
            csrc[(size_t)d * PAD + pos] = s;
        }
        return;
    }
    int w = threadIdx.x >> 6, l = threadIdx.x & 63;
    int m0 = blockIdx.x * 16;
    int c = l & 15, g = l >> 4;
    int xr = m0 + c; if (xr >= N) xr = N - 1;
    bf16x8 af[4];
    const float* arow = x + (size_t)xr * 128 + 8 * g;
#pragma unroll
    for (int ks = 0; ks < 4; ++ks) {
        float4 f0 = *(const float4*)(arow + 32 * ks);
        float4 f1 = *(const float4*)(arow + 32 * ks + 4);
        bf16x8 t;
        t[0] = (short)f2bf(f0.x); t[1] = (short)f2bf(f0.y);
        t[2] = (short)f2bf(f0.z); t[3] = (short)f2bf(f0.w);
        t[4] = (short)f2bf(f1.x); t[5] = (short)f2bf(f1.y);
        t[6] = (short)f2bf(f1.z); t[7] = (short)f2bf(f1.w);
        af[ks] = t;
    }
    f32x4 acc = {};
    const unsigned short* brow = W1T + (size_t)(16 * w + c) * 128 + 8 * g;
#pragma unroll
    for (int ks = 0; ks < 4; ++ks) acc = MFMA(af[ks], ldb8(brow + 32 * ks), acc);
    int j = 16 * w + c;
    float bj = b1[j];
#pragma unroll
    for (int r = 0; r < 4; ++r) {
        float v = fmaxf(acc[r] + bj, 0.f);
        unsigned short us = f2bf(v);
        int row = m0 + 4 * g + r;
        if (row < N) h0b[(size_t)row * 64 + j] = us;
        h0s[4 * g + r][j] = us;
    }
    __syncthreads();
    // alpha via MFMA on wave 0: alpha[row][t] = sum_k h0[row][k] * vaT[t][k]
    if (w == 0) {
        bf16x8 a0 = ldb8(&h0s[c][8 * g]);
        bf16x8 a1 = ldb8(&h0s[c][32 + 8 * g]);
        bf16x8 b0 = ldb8(&vaT[c * 64 + 8 * g]);
        bf16x8 b1v = ldb8(&vaT[c * 64 + 32 + 8 * g]);
        f32x4 al = {};
        al = MFMA(a0, b0, al);
        al = MFMA(a1, b1v, al);
#pragma unroll
        for (int r = 0; r < 4; ++r) {
            int n = m0 + 4 * g + r;
            if (n < N) {
                if (c < 8) asrc[n * 8 + c] = al[r];
                else       adst[n * 8 + (c - 8)] = al[r];
            }
        }
    }
}

// ---------------- conv1 aggregation: per-head aggregate, half-wave 2-edge ushort2 gather ----------------

__global__ __launch_bounds__(128) void k_conv1agg(const unsigned short* __restrict__ h0b,
                                                  const float* __restrict__ asrc, const float* __restrict__ adst,
                                                  const int* __restrict__ degs, const int* __restrict__ csrc,
                                                  unsigned short* __restrict__ aggb, int N) {
    __shared__ int srcb[PAD];
    __shared__ float sb[PAD][8];
    __shared__ float mx[8], den[8], adl[8];
    __shared__ float accsh[512];
    int tid = threadIdx.x;
    int n = blockIdx.x;
    int deg = degs[n];
    if (tid < 8) adl[tid] = adst[n * 8 + tid];
    __syncthreads();
    if (tid < deg) {
        int s = csrc[(size_t)n * PAD + tid];
        srcb[tid] = s;
        const float4* ap = (const float4*)&asrc[(size_t)s * 8];
        float4 a0 = ap[0], a1 = ap[1];
        float v;
        v = a0.x + adl[0]; sb[tid][0] = (v >= 0.f) ? v : NEG * v;
        v = a0.y + adl[1]; sb[tid][1] = (v >= 0.f) ? v : NEG * v;
        v = a0.z + adl[2]; sb[tid][2] = (v >= 0.f) ? v : NEG * v;
        v = a0.w + adl[3]; sb[tid][3] = (v >= 0.f) ? v : NEG * v;
        v = a1.x + adl[4]; sb[tid][4] = (v >= 0.f) ? v : NEG * v;
        v = a1.y + adl[5]; sb[tid][5] = (v >= 0.f) ? v : NEG * v;
        v = a1.z + adl[6]; sb[tid][6] = (v >= 0.f) ? v : NEG * v;
        v = a1.w + adl[7]; sb[tid][7] = (v >= 0.f) ? v : NEG * v;
    }
    __syncthreads();
    if (tid < 64) {
        int hh = tid & 7, idx = tid >> 3;
        float m = -1e30f;
        for (int i = idx; i < deg; i += 8) m = fmaxf(m, sb[i][hh]);
        m = fmaxf(m, __shfl_xor(m, 8));
        m = fmaxf(m, __shfl_xor(m, 16));
        m = fmaxf(m, __shfl_xor(m, 32));
        if (tid < 8) mx[tid] = m;
    }
    __syncthreads();
    // merged exp + denominator pass
    if (tid < 64) {
        int hh = tid & 7, idx = tid >> 3;
        float mh = mx[hh];
        float d = 0.f;
        for (int i = idx; i < deg; i += 8) {
            float e = __expf(sb[i][hh] - mh);
            sb[i][hh] = e;
            d += e;
        }
        d += __shfl_xor(d, 8);
        d += __shfl_xor(d, 16);
        d += __shfl_xor(d, 32);
        if (tid < 8) den[tid] = d + 1e-16f;
    }
    __syncthreads();
    // gather: wave wv takes edge pairs; half-wave = edge parity; lane covers 2 channels (ushort2)
    int lane = tid & 63, wv = tid >> 6;
    int half = lane >> 5, cl = lane & 31;
    float accA[8] = {0.f, 0.f, 0.f, 0.f, 0.f, 0.f, 0.f, 0.f};
    float accB[8] = {0.f, 0.f, 0.f, 0.f, 0.f, 0.f, 0.f, 0.f};
    for (int i = 2 * wv; i < deg; i += 4) {
        int e = i + half;
        float vx = 0.f, vy = 0.f;
        float4 w0 = {0.f, 0.f, 0.f, 0.f}, w1 = {0.f, 0.f, 0.f, 0.f};
        if (e < deg) {
            unsigned u = *(const unsigned*)&h0b[(size_t)srcb[e] * 64 + 2 * cl];
            vx = bf2f((unsigned short)(u & 0xFFFFu));
            vy = bf2f((unsigned short)(u >> 16));
            w0 = *(const float4*)&sb[e][0];
            w1 = *(const float4*)&sb[e][4];
        }
        accA[0] += w0.x * vx; accB[0] += w0.x * vy;
        accA[1] += w0.y * vx; accB[1] += w0.y * vy;
        accA[2] += w0.z * vx; accB[2] += w0.z * vy;
        accA[3] += w0.w * vx; accB[3] += w0.w * vy;
        accA[4] += w1.x * vx; accB[4] += w1.x * vy;
        accA[5] += w1.y * vx; accB[5] += w1.y * vy;
        accA[6] += w1.z * vx; accB[6] += w1.z * vy;
        accA[7] += w1.w * vx; accB[7] += w1.w * vy;
    }
#pragma unroll
    for (int h = 0; h < 8; ++h) {
        accA[h] += __shfl_xor(accA[h], 32);
        accB[h] += __shfl_xor(accB[h], 32);
    }
    __syncthreads();
    if (wv == 1 && half == 0) {
#pragma unroll
        for (int h = 0; h < 8; ++h) {
            accsh[h * 64 + 2 * cl] = accA[h];
            accsh[h * 64 + 2 * cl + 1] = accB[h];
        }
    }
    __syncthreads();
    if (wv == 0 && half == 0) {
#pragma unroll
        for (int h = 0; h < 8; ++h) {
            float t0 = (accA[h] + accsh[h * 64 + 2 * cl]) / den[h];
            float t1 = (accB[h] + accsh[h * 64 + 2 * cl + 1]) / den[h];
            unsigned uo = (unsigned)f2bf(t0) | ((unsigned)f2bf(t1) << 16);
            *(unsigned*)&aggb[(size_t)n * 512 + h * 64 + 2 * cl] = uo;
        }
    }
}

// ---------------- fused post1+linc2 (MFMA, 4 waves): h1 tile LDS-only; no split-K partials ----------------
// phase 1: wave w computes heads {2w, 2w+1} of h1 = elu(agg_h @ Wc1_h + bc1) into LDS
// phase 2: wave w computes output cols [16w,16w+16) over full K=512 (16 MFMAs, no reduction)

__global__ __launch_bounds__(256) void k_p1l2(const unsigned short* __restrict__ aggb,
                                              const unsigned short* __restrict__ Wc1T,
                                              const float* __restrict__ bc1,
                                              const unsigned short* __restrict__ Wc2T,
                                              const float* __restrict__ as2, const float* __restrict__ ad2,
                                              unsigned short* __restrict__ hc2b,
                                              float* __restrict__ asrc, float* __restrict__ adst, int N) {
    __shared__ unsigned short h1s[16][520];   // 16.6KB, stride 520 -> 1040B rows: 2-way bank alias only
    __shared__ float pps[4][16][2];           // 512B cross-wave alpha partials
    int w = threadIdx.x >> 6, l = threadIdx.x & 63;
    int m0 = blockIdx.x * 16;
    int c = l & 15, g = l >> 4;
    // phase 1
#pragma unroll
    for (int hl = 0; hl < 2; ++hl) {
        int h = 2 * w + hl;
        const unsigned short* arow = aggb + (size_t)(m0 + c) * 512 + h * 64 + 8 * g;
        bf16x8 af0 = ldb8(arow), af1 = ldb8(arow + 32);
        f32x4 acc[4] = {};
#pragma unroll
        for (int nt = 0; nt < 4; ++nt) {
            const unsigned short* brow = Wc1T + (size_t)(h * 64 + 16 * nt + c) * 64 + 8 * g;
            acc[nt] = MFMA(af0, ldb8(brow), acc[nt]);
            acc[nt] = MFMA(af1, ldb8(brow + 32), acc[nt]);
        }
#pragma unroll
        for (int nt = 0; nt < 4; ++nt) {
            int j = h * 64 + 16 * nt + c;
            float bj = bc1[j];
#pragma unroll
            for (int r = 0; r < 4; ++r) {
                float v = acc[nt][r] + bj;
                v = (v > 0.f) ? v : __expf(v) - 1.f;
                h1s[4 * g + r][j] = f2bf(v);
            }
        }
    }
    __syncthreads();
    // phase 2: full-K per-wave col tile
    f32x4 acc2 = {};
    const unsigned short* brow2 = Wc2T + (size_t)(16 * w + c) * 512 + 8 * g;
#pragma unroll 4
    for (int ks = 0; ks < 16; ++ks) {
        bf16x8 af = ldb8(&h1s[c][32 * ks + 8 * g]);
        acc2 = MFMA(af, ldb8(brow2 + 32 * ks), acc2);
    }
    int j = 16 * w + c;
    float aj = as2[j], dj = ad2[j];
    float ps[4], pd[4];
#pragma unroll
    for (int r = 0; r < 4; ++r) {
        float v = acc2[r];
        hc2b[(size_t)(m0 + 4 * g + r) * 64 + j] = f2bf(v);
        ps[r] = v * aj;
        pd[r] = v * dj;
    }
#pragma unroll
    for (int r = 0; r < 4; ++r) {
        float s = ps[r], d = pd[r];
        s += __shfl_xor(s, 1); s += __shfl_xor(s, 2); s += __shfl_xor(s, 4); s += __shfl_xor(s, 8);
        d += __shfl_xor(d, 1); d += __shfl_xor(d, 2); d += __shfl_xor(d, 4); d += __shfl_xor(d, 8);
        if (c == 0) {
            pps[w][4 * g + r][0] = s;
            pps[w][4 * g + r][1] = d;
        }
    }
    __syncthreads();
    int tid = threadIdx.x;
    if (tid < 32) {
        int row = tid >> 1, sel = tid & 1;
        float sum = pps[0][row][sel] + pps[1][row][sel] + pps[2][row][sel] + pps[3][row][sel];
        int n = m0 + row;
        if (n < N) {
            if (sel == 0) asrc[n] = sum;
            else          adst[n] = sum;
        }
    }
}

// ---------------- conv2 + fused final: half-wave 2-edge ushort2 gather ----------------

__global__ __launch_bounds__(256) void k_conv2f(const unsigned short* __restrict__ hc2b,
                                                const float* __restrict__ asrc, const float* __restrict__ adst,
                                                const int* __restrict__ degs, const int* __restrict__ csrc,
                                                const float* __restrict__ bc2,
                                                const float* __restrict__ W2, const float* __restrict__ b2,
                                                float* __restrict__ out, int N) {
    __shared__ float w2s[HID * OUT_CH];  // 10KB
    __shared__ float cosh_[4][HID];      // 1KB
    int tid = threadIdx.x;
    for (int i = tid; i < HID * OUT_CH; i += 256) w2s[i] = W2[i];
    int lane = tid & 63, nl = tid >> 6;
    int half = lane >> 5, cl = lane & 31;
    int n = blockIdx.x * 4 + nl;
    if (n < N) {
        int deg = degs[n];
        float ad = adst[n];
        float rm = -1e30f, rden = 0.f;
        float ax = 0.f, ay = 0.f;
        for (int base = 0; base < deg; base += 64) {
            int cnt = min(64, deg - base);
            int s = 0;
            float sc = -1e30f;
            if (lane < cnt) {
                s = csrc[(size_t)n * PAD + base + lane];
                float v = asrc[s] + ad;
                sc = (v >= 0.f) ? v : NEG * v;
            }
            float m = sc;
#pragma unroll
            for (int mm = 1; mm < 64; mm <<= 1) m = fmaxf(m, __shfl_xor(m, mm));
            float nmv = fmaxf(rm, m);
            float scale = __expf(rm - nmv);
            float p = (lane < cnt) ? __expf(sc - nmv) : 0.f;
            float d = p;
#pragma unroll
            for (int mm = 1; mm < 64; mm <<= 1) d += __shfl_xor(d, mm);
            rden = rden * scale + d;
            rm = nmv;
            ax *= scale; ay *= scale;
            for (int i = 0; i < cnt; i += 2) {
                int idx = i + half;
                float pi = __shfl(p, idx);
                int si = __shfl(s, idx);
                unsigned u = *(const unsigned*)&hc2b[(size_t)si * 64 + 2 * cl];
                ax += pi * bf2f((unsigned short)(u & 0xFFFFu));
                ay += pi * bf2f((unsigned short)(u >> 16));
            }
        }
        ax += __shfl_xor(ax, 32);
        ay += __shfl_xor(ay, 32);
        if (half == 0) {
            float inv = 1.f / (rden + 1e-16f);
            cosh_[nl][2 * cl] = ax * inv + bc2[2 * cl];
            cosh_[nl][2 * cl + 1] = ay * inv + bc2[2 * cl + 1];
        }
    }
    __syncthreads();
    if (tid >= 160) return;
    int nn = tid / 40, j = tid % 40;
    int no = blockIdx.x * 4 + nn;
    if (no >= N) return;
    float s = b2[j];
#pragma unroll 8
    for (int k = 0; k < HID; ++k) s += cosh_[nn][k] * w2s[k * OUT_CH + j];
    out[(size_t)no * OUT_CH + j] = s;
}

// ---------------- host ----------------

extern "C" void kernel_launch(void* const* d_in, const int* in_sizes, int n_in,
                              void* d_out, int out_size, void* d_ws, size_t ws_size,
                              hipStream_t stream) {
    const float* x   = (const float*)d_in[0];
    const int*   ei  = (const int*)d_in[1];
    const float* W1  = (const float*)d_in[2];
    const float* b1  = (const float*)d_in[3];
    const float* Wc1 = (const float*)d_in[4];
    const float* as1 = (const float*)d_in[5];
    const float* ad1 = (const float*)d_in[6];
    const float* bc1 = (const float*)d_in[7];
    const float* Wc2 = (const float*)d_in[8];
    const float* as2 = (const float*)d_in[9];
    const float* ad2 = (const float*)d_in[10];
    const float* bc2 = (const float*)d_in[11];
    const float* W2  = (const float*)d_in[12];
    const float* b2  = (const float*)d_in[13];

    const int N = in_sizes[0] / IN_CH;
    const int E = in_sizes[1] / 2;
    const int T = E + N;

    char* base = (char*)d_ws;
    size_t off = 0;
    auto carve = [&](size_t bytes) -> void* {
        off = (off + 255) & ~(size_t)255;
        void* r = base + off;
        off += bytes;
        return r;
    };
    int* cursor     = (int*)carve((size_t)N * 4);
    int* csrc       = (int*)carve((size_t)N * PAD * 4);
    unsigned short* W1T  = (unsigned short*)carve((size_t)64 * 128 * 2);
    unsigned short* Wc1T = (unsigned short*)carve((size_t)512 * 64 * 2);
    unsigned short* Wc2T = (unsigned short*)carve((size_t)64 * 512 * 2);
    unsigned short* vaT  = (unsigned short*)carve((size_t)16 * 64 * 2);
    unsigned short* h0b  = (unsigned short*)carve((size_t)N * 64 * 2);
    float* asrc1    = (float*)carve((size_t)N * 8 * 4);
    float* adst1    = (float*)carve((size_t)N * 8 * 4);
    unsigned short* aggb = (unsigned short*)carve((size_t)N * 512 * 2);
    unsigned short* hc2b = (unsigned short*)carve((size_t)N * 64 * 2);
    float* asrc2    = (float*)carve((size_t)N * 4);
    float* adst2    = (float*)carve((size_t)N * 4);

    int init_total = N + 64 * 128 + 512 * 64 + 64 * 512 + 1024;
    k_init<<<(init_total + 255) / 256, 256, 0, stream>>>(W1, Wc1, Wc2, as1, ad1, cursor,
                                                         W1T, Wc1T, Wc2T, vaT, N);

    int NB = (N + 15) / 16;
    int FB = (T + 255) / 256;
    k_lin1m<<<NB + FB, 256, 0, stream>>>(x, W1T, b1, vaT, h0b, asrc1, adst1,
                                         ei, E, T, cursor, csrc, N, NB);
    k_conv1agg<<<N, 128, 0, stream>>>(h0b, asrc1, adst1, cursor, csrc, aggb, N);
    k_p1l2<<<(N + 15) / 16, 256, 0, stream>>>(aggb, Wc1T, bc1, Wc2T, as2, ad2,
                                              hc2b, asrc2, adst2, N);
    k_conv2f<<<(N + 3) / 4, 256, 0, stream>>>(hc2b, asrc2, adst2, cursor, csrc, bc2, W2, b2,
                                              (float*)d_out, N);
}